// Round 4
// baseline (393.069 us; speedup 1.0000x reference)
//
#include <hip/hip_runtime.h>

// Problem constants (fixed by the reference)
#define H_DIM   1024
#define G_DIM   128
#define N_DIM   384            // 3*G
#define M_TOTAL 65536          // 32*2048 rows
#define BM      64             // rows per block
// LDS x-buffer: 64 rows x 32 f16 = 4 KB, ring of 4 (16 KB)

typedef _Float16 half8  __attribute__((ext_vector_type(8)));
typedef _Float16 half4  __attribute__((ext_vector_type(4)));
typedef __fp16   fp16x2 __attribute__((ext_vector_type(2)));
typedef float    f32x4  __attribute__((ext_vector_type(4)));

__device__ __forceinline__ float fast_sigmoid(float v) {
    return 1.0f / (1.0f + __expf(-v));
}
__device__ __forceinline__ float fast_tanh(float v) {
    return 1.0f - 2.0f / (__expf(2.0f * v) + 1.0f);
}

// 4 f32 -> 4 f16 with RTZ (same rounding as previous rounds)
__device__ __forceinline__ half4 cvt4(f32x4 v) {
    fp16x2 p0 = __builtin_amdgcn_cvt_pkrtz(v[0], v[1]);
    fp16x2 p1 = __builtin_amdgcn_cvt_pkrtz(v[2], v[3]);
    half4 h;
    h[0] = (_Float16)p0[0]; h[1] = (_Float16)p0[1];
    h[2] = (_Float16)p1[0]; h[3] = (_Float16)p1[1];
    return h;
}

// weight_ih (384x1024 fp32 row-major = B^T, K contiguous) -> f16 fragments.
// NEW lane-contiguous layout: for group (wv, ktg), lane l holds its THREE
// ct-fragments (ct = wv, wv+8, wv+16) back-to-back:
//   wf[((wv*32 + ktg)*64 + l)*24 + i*8 + j]
//     = f16( W[(wv+8i)*16 + (l&15)][ktg*32 + (l>>4)*8 + j] )
// So in the main loop ONE base register serves 6 loads (this step + next) via
// immediate offsets 0/16/32 and 3072/3088/3104 bytes.
__global__ __launch_bounds__(256) void prep_w_kernel(const float* __restrict__ w,
                                                     _Float16* __restrict__ wf) {
    int tid  = blockIdx.x * 256 + threadIdx.x;   // 0 .. 16383
    int lane = tid & 63;
    int grp  = tid >> 6;        // wv*32 + ktg : 0..255
    int wv   = grp >> 5;
    int ktg  = grp & 31;
    int ln   = lane & 15;
    int kb   = ktg * 32 + (lane >> 4) * 8;
    _Float16* dst = wf + ((size_t)grp * 64 + lane) * 24;
    #pragma unroll
    for (int i = 0; i < 3; ++i) {
        int col = (wv + 8 * i) * 16 + ln;
        const f32x4* src = (const f32x4*)(w + (size_t)col * H_DIM + kb);
        f32x4 v0 = src[0], v1 = src[1];
        half8 h;
        #pragma unroll
        for (int j = 0; j < 4; ++j) { h[j] = (_Float16)v0[j]; h[4 + j] = (_Float16)v1[j]; }
        *(half8*)(dst + i * 8) = h;
    }
}

// ---- raw barrier: lgkmcnt(0) drain only, vmcnt prefetches stay in flight ----
#define FENCE() asm volatile("" ::: "memory")
#define WAITLGKM0() { FENCE(); __builtin_amdgcn_s_waitcnt(0xC07F); FENCE(); }
#define BARRW()     { WAITLGKM0(); __builtin_amdgcn_s_barrier(); FENCE(); }

__global__ __launch_bounds__(512, 4) void ping_main_kernel(
    const float* __restrict__ x, const _Float16* __restrict__ wf,
    const float* __restrict__ bias_ih, const float* __restrict__ bias_hh,
    const float* __restrict__ lin_w, const float* __restrict__ lin_b,
    float* __restrict__ out)
{
    __shared__ _Float16 shX[4 * 2048];   // 16 KB: ring of 4 buffers, 64x32 f16
    __shared__ float sh_out[BM];

    const int t    = threadIdx.x;       // 0..511
    const int lane = t & 63;
    const int wv   = t >> 6;            // wave 0..7
    const int ln   = lane & 15;
    const int quad = lane >> 4;

    if (t < BM) sh_out[t] = 0.0f;

    const size_t row0 = (size_t)blockIdx.x * BM;

    // --- reg-staged x path: wave wv stages rows 8wv..8wv+7 ---
    const int drow = wv * 8 + (lane >> 3);                 // 0..63
    const int dcol = (lane & 7) * 4;
    const float* xsrc = x + (row0 + drow) * (size_t)H_DIM + dcol;
    _Float16* wdst = &shX[drow * 32 + dcol];               // + ring*2048 elems

    // --- A fragment read base: lane (ln,quad), rt: A[rt*16+ln][quad*8..+8]
    const char* aBase = (const char*)&shX[0] + ln * 64 + quad * 16;  // + rt*1024 + ring*4096

    // --- B fragment base (new contiguous layout): step K at pb + K*1536 halves
    const _Float16* pb = wf + ((size_t)(wv * 32) * 64 + lane) * 24;

    f32x4 acc[3][4];
    #pragma unroll
    for (int i = 0; i < 3; ++i)
        #pragma unroll
        for (int rt = 0; rt < 4; ++rt)
            acc[i][rt] = (f32x4){0.f, 0.f, 0.f, 0.f};

    // Pipeline:
    //   g ring 4   : G(s) issued at s-6..s-4 (slot (s)&3), staged (cvt+ds_write)
    //                at s-2, read (MFMA) at s. True in-flight: 4 steps.
    //   bf 2 groups: group covering steps (2m,2m+1) loaded 6-at-a-time at step
    //                2m-3 (odd), AFTER stage/G-order so its wait drains only
    //                the G consumed that same step. Slot = m&1 -> compile-time.
    //   barriers   : end of odd steps only (16 total).
    f32x4 g[4];
    half8 bf[2][6];

    // group load for steps (S, S+1) -> slot (S>>1)&1; one base, imm offsets
#define BLOAD(S) { \
    const _Float16* pbS = pb + (size_t)(S) * 1536; \
    _Pragma("unroll") \
    for (int i = 0; i < 3; ++i) { \
        bf[((S) >> 1) & 1][i]     = *(const half8*)(pbS + i * 8); \
        bf[((S) >> 1) & 1][3 + i] = *(const half8*)(pbS + 1536 + i * 8); \
    } }

    // --- prologue (queue order: G0, G1, bgrp01, bgrp23, G2, G3, G4, G5) ---
    g[0] = *(const f32x4*)(xsrc);                       // G0
    g[1] = *(const f32x4*)(xsrc + 32);                  // G1
    BLOAD(0);                                           // slot0 <- steps 0,1
    BLOAD(2);                                           // slot1 <- steps 2,3
    g[2] = *(const f32x4*)(xsrc + 64);                  // G2
    g[3] = *(const f32x4*)(xsrc + 96);                  // G3
    *(half4*)(wdst)        = cvt4(g[0]);                // stage buf0 (waits G0)
    *(half4*)(wdst + 2048) = cvt4(g[1]);                // stage buf1 (waits G1)
    g[0] = *(const f32x4*)(xsrc + 128);                 // G4 (slot0 freed)
    g[1] = *(const f32x4*)(xsrc + 160);                 // G5
    BARRW();                                            // buf0/buf1 visible

    // Step K (order matters for the vmcnt queue):
    //   1) MFMA(K)            — waits bgrp; drains only G(K+2) (consumed in 2)
    //   2) stage buf(K+2)     — waits G(K+2) (already retired by 1)
    //   3) BLOAD(K+3) odd K   — queue position: before this step's G-issue
    //   4) issue G(K+6)       — into slot (K+2)&3, just freed by 2
    //   5) barrier on odd K
#define STEP(K, DO_G, DO_B, DO_S, DO_BAR) { \
    _Pragma("unroll") \
    for (int rt = 0; rt < 4; ++rt) { \
        half8 afr = *(const half8*)(aBase + ((K) & 3) * 4096 + rt * 1024); \
        _Pragma("unroll") \
        for (int i = 0; i < 3; ++i) \
            acc[i][rt] = __builtin_amdgcn_mfma_f32_16x16x32_f16(afr, bf[((K) >> 1) & 1][((K) & 1) * 3 + i], acc[i][rt], 0, 0, 0); \
    } \
    if (DO_S) *(half4*)(wdst + (((K) + 2) & 3) * 2048) = cvt4(g[((K) + 2) & 3]); \
    if (DO_B) BLOAD((K) + 3); \
    if (DO_G) g[((K) + 6) & 3] = *(const f32x4*)(xsrc + (size_t)((K) + 6) * 32); \
    if (DO_BAR) BARRW(); }

    // K = 0..23 (kb multiple of 4 keeps all register indices compile-time)
    for (int kb = 0; kb < 24; kb += 4) {
        STEP(kb + 0, true, false, true, false);
        STEP(kb + 1, true, true,  true, true);    // loads group (kb+4, kb+5)
        STEP(kb + 2, true, false, true, false);
        STEP(kb + 3, true, true,  true, true);    // loads group (kb+6, kb+7)
    }
    // tail
    STEP(24, true,  false, true,  false);   // issues G30
    STEP(25, true,  true,  true,  true);    // issues G31, loads group (28,29)
    STEP(26, false, false, true,  false);
    STEP(27, false, true,  true,  true);    // loads group (30,31)
    STEP(28, false, false, true,  false);   // stages buf for step 30
    STEP(29, false, false, true,  true);    // stages buf for step 31
    STEP(30, false, false, false, false);
    STEP(31, false, false, false, false);

    // --- Epilogue: gate column g = 16*wv + ln; acc[0]=r, acc[1]=z, acc[2]=n ---
    const int g_col = 16 * wv + ln;
    const float b_ir = bias_ih[g_col];
    const float b_iz = bias_ih[G_DIM + g_col];
    const float b_in = bias_ih[2 * G_DIM + g_col];
    const float b_hr = bias_hh[g_col];
    const float b_hz = bias_hh[G_DIM + g_col];
    const float b_hn = bias_hh[2 * G_DIM + g_col];
    const float lw   = lin_w[g_col];

    #pragma unroll
    for (int rt = 0; rt < 4; ++rt) {
        #pragma unroll
        for (int reg = 0; reg < 4; ++reg) {
            const float r = fast_sigmoid(acc[0][rt][reg] + b_ir + b_hr);
            const float z = fast_sigmoid(acc[1][rt][reg] + b_iz + b_hz);
            const float n = fast_tanh(acc[2][rt][reg] + b_in + r * b_hn);
            float v = lw * (1.0f - z) * n;
            // reduce over the 16 gate columns held by this quad-row group
            v += __shfl_xor(v, 1);
            v += __shfl_xor(v, 2);
            v += __shfl_xor(v, 4);
            v += __shfl_xor(v, 8);
            if (ln == 0) atomicAdd(&sh_out[rt * 16 + quad * 4 + reg], v);
        }
    }

    __syncthreads();
    if (t < BM) out[row0 + t] = sh_out[t] + lin_b[0];
}

extern "C" void kernel_launch(void* const* d_in, const int* in_sizes, int n_in,
                              void* d_out, int out_size, void* d_ws, size_t ws_size,
                              hipStream_t stream) {
    const float* x      = (const float*)d_in[0];
    const float* w_ih   = (const float*)d_in[1];
    // d_in[2] = weight_hh: unused (hidden state is always zero in the reference)
    const float* b_ih   = (const float*)d_in[3];
    const float* b_hh   = (const float*)d_in[4];
    const float* lin_w  = (const float*)d_in[5];
    const float* lin_b  = (const float*)d_in[6];
    float* out          = (float*)d_out;
    _Float16* wf        = (_Float16*)d_ws;   // 256*64*24*2 = 768 KB scratch

    hipLaunchKernelGGL(prep_w_kernel, dim3(64), dim3(256), 0, stream,
                       w_ih, wf);
    hipLaunchKernelGGL(ping_main_kernel, dim3(M_TOTAL / BM), dim3(512), 0, stream,
                       x, wf, b_ih, b_hh, lin_w, lin_b, out);
}